// Round 11
// baseline (51.149 us; speedup 1.0000x reference)
//
#include <hip/hip_runtime.h>

typedef float v2f __attribute__((ext_vector_type(2)));

#define IMG 512
#define OUT_N 502
#define NPLANE 48
#define NSTRIP 32            // 16 output rows per strip
#define SROWS 16
#define C1c 0.0001f
#define C2c 0.0004f
#define EODD 264             // odd-col region offset (float4 units) in row buffer

// ssim from H-blurred (Bs, Bd, BP, BM) where s=x+y, d=x-y:
// mux=(Bs+Bd)/2, muy=(Bs-Bd)/2; BP=blur(s^2), BM=blur(d^2).
__device__ __forceinline__ float ssim_px(float Bs, float Bd, float BP, float BM) {
    float mx = 0.5f*(Bs + Bd), my = 0.5f*(Bs - Bd);
    float A = mx*mx, B = my*my, mxy = mx*my;
    float sumsq = 0.5f*(BP + BM) - A - B;   // sigx2 + sigy2
    float sxy   = 0.25f*(BP - BM) - mxy;    // sigxy
    float num = (2.f*mxy + C1c) * (2.f*sxy + C2c);
    float den = (A + B + C1c) * (sumsq + C2c);
    return num / den;
}

// 512 threads, 1 col/thread, pair-iterations (2 rows per barrier).
// V-ring: 12 rows of (s,d) float2 = 24 VGPR -> total <64 -> 8 waves/SIMD.
// grid 32x48=1536 blocks -> 4 blocks/CU = 32 waves/CU. Raw s_barrier +
// lgkmcnt(0) only (no vmcnt drain: prefetched loads stay in flight).
// pk-math: (s,d) and (P,M) packed in v2f -> v_pk_fma_f32.
__global__ __launch_bounds__(512, 4) void ssim_strip(
    const float* __restrict__ in, const float* __restrict__ tgt,
    const float* __restrict__ w, float* __restrict__ partial)
{
    __shared__ float4 buf[2][2][528];   // [pair parity][row in pair][parity col]
    __shared__ float g1s[16];
    __shared__ float red[8];

    const int tid   = threadIdx.x;
    const int strip = blockIdx.x;
    const int plane = blockIdx.y;
    const int r0 = strip * SROWS;
    const float* __restrict__ ip = in  + (size_t)plane * (IMG*IMG);
    const float* __restrict__ tp = tgt + (size_t)plane * (IMG*IMG);

    // 1D factor = row sums of 2D kernel (exact: w2d = outer(g,g), sum g = 1)
    if (tid < 11) {
        float s = 0.f;
        #pragma unroll
        for (int j = 0; j < 11; ++j) s += w[tid*11 + j];
        g1s[tid] = s;
    }
    __syncthreads();
    float g[11];
    #pragma unroll
    for (int j = 0; j < 11; ++j)
        g[j] = __int_as_float(__builtin_amdgcn_readfirstlane(__float_as_int(g1s[j])));

    v2f sd[12];                 // ring: pair slot p -> entries 2p, 2p+1
    float acc = 0.f;
    const int wcol = (tid >> 1) + (tid & 1) * EODD;   // V-write slot for col tid
    const int hrow = tid >> 8;                        // H: row within pair
    const int ht   = tid & 255;                       // H: col-pair index
    const int c0   = 2 * ht;

    float xA0, yA0, xA1, yA1;   // prefetch set A
    float xB0, yB0, xB1, yB1;   // prefetch set B (prologue staggering)

#define ISSUE_A(P) \
    { const int ra = r0 + 2*(P); \
      xA0 = (ra   < IMG) ? ip[ra*IMG + tid]     : 0.f; \
      yA0 = (ra   < IMG) ? tp[ra*IMG + tid]     : 0.f; \
      xA1 = (ra+1 < IMG) ? ip[(ra+1)*IMG + tid] : 0.f; \
      yA1 = (ra+1 < IMG) ? tp[(ra+1)*IMG + tid] : 0.f; }
#define ISSUE_B(P) \
    { const int ra = r0 + 2*(P); \
      xB0 = (ra   < IMG) ? ip[ra*IMG + tid]     : 0.f; \
      yB0 = (ra   < IMG) ? tp[ra*IMG + tid]     : 0.f; \
      xB1 = (ra+1 < IMG) ? ip[(ra+1)*IMG + tid] : 0.f; \
      yB1 = (ra+1 < IMG) ? tp[(ra+1)*IMG + tid] : 0.f; }
#define INSP_A(SL) \
    sd[2*(SL)  ] = (v2f){xA0 + yA0, xA0 - yA0}; \
    sd[2*(SL)+1] = (v2f){xA1 + yA1, xA1 - yA1};
#define INSP_B(SL) \
    sd[2*(SL)  ] = (v2f){xB0 + yB0, xB0 - yB0}; \
    sd[2*(SL)+1] = (v2f){xB1 + yB1, xB1 - yB1};

    // V-blur pair T: rows 2T (j=0..10, g[j]) and 2T+1 (j=1..11, g[j-1]).
    // Row 2T+j at sd[2*((T+(j>>1))%6) + (j&1)]; squares shared by both rows.
#define VWR(T) \
    { v2f a0=(v2f)(0.f), p0=(v2f)(0.f), a1=(v2f)(0.f), p1=(v2f)(0.f); \
      _Pragma("unroll") \
      for (int j = 0; j <= 11; ++j) { \
        v2f s = sd[2*(((T) + (j>>1)) % 6) + (j&1)]; \
        v2f q = s * s; \
        if (j <= 10) { const float wj = g[j];   a0 += wj*s; p0 += wj*q; } \
        if (j >= 1)  { const float wj = g[j-1]; a1 += wj*s; p1 += wj*q; } \
      } \
      buf[(T)&1][0][wcol] = make_float4(a0.x, a0.y, p0.x, p0.y); \
      buf[(T)&1][1][wcol] = make_float4(a1.x, a1.y, p1.x, p1.y); }

#define HPASS(T) \
    { const int oy = r0 + 2*(T) + hrow; \
      if (oy < OUT_N && c0 < OUT_N) { \
        v2f As=(v2f)(0.f), Ap=(v2f)(0.f), Bs_=(v2f)(0.f), Bp=(v2f)(0.f); \
        _Pragma("unroll") \
        for (int j = 0; j < 12; ++j) { \
          float4 v = buf[(T)&1][hrow][ht + (j>>1) + (j&1)*EODD]; \
          v2f vs = (v2f){v.x, v.y}, vp = (v2f){v.z, v.w}; \
          if (j <= 10) { const float wj = g[j];   As  += wj*vs; Ap += wj*vp; } \
          if (j >= 1)  { const float wj = g[j-1]; Bs_ += wj*vs; Bp += wj*vp; } \
        } \
        acc += ssim_px(As.x, As.y, Ap.x, Ap.y); \
        if (c0 + 1 < OUT_N) acc += ssim_px(Bs_.x, Bs_.y, Bp.x, Bp.y); \
      } }

    // ds_writes committed -> rendezvous -> pin schedule. vmcnt NEVER drained
    // here: prefetched global loads stay in flight across the barrier.
#define BARRIER() \
    asm volatile("s_waitcnt lgkmcnt(0)" ::: "memory"); \
    __builtin_amdgcn_s_barrier(); \
    __builtin_amdgcn_sched_barrier(0);

    // Iter T: issue pair T+6 loads, V-blur pair T, write LDS, barrier,
    // H-pass pair T, then insert prefetched pair into slot T%6 (vacated).
    // Load->consume gap ~= one full iteration of VALU+LDS work.
#define ITER(T) \
    { if ((T) <= 6) ISSUE_A((T)+6) \
      VWR(T) \
      BARRIER() \
      HPASS(T) \
      if ((T) <= 6) INSP_A((T)%6) }

    // Prologue: pairs 0..5 into ring, depth-2 staggered issue.
    ISSUE_A(0) ISSUE_B(1)
    INSP_A(0)  ISSUE_A(2)
    INSP_B(1)  ISSUE_B(3)
    INSP_A(2)  ISSUE_A(4)
    INSP_B(3)  ISSUE_B(5)
    INSP_A(4)  INSP_B(5)

    // Main: 8 pair-iterations -> 16 output rows (pairs 0..12 = 26 input rows).
    ITER(0) ITER(1) ITER(2) ITER(3)
    ITER(4) ITER(5) ITER(6) ITER(7)

    // block reduction: wave shuffle, then 8 wave-partials through LDS
    #pragma unroll
    for (int off = 32; off > 0; off >>= 1)
        acc += __shfl_down(acc, off, 64);
    const int lane = tid & 63, wv = tid >> 6;
    if (lane == 0) red[wv] = acc;
    __syncthreads();
    if (tid == 0) {
        float t = 0.f;
        #pragma unroll
        for (int i = 0; i < 8; ++i) t += red[i];
        partial[plane * NSTRIP + strip] = t;
    }
}

// Deterministic final reduction: fixed traversal, double accumulation.
__global__ __launch_bounds__(256) void ssim_final(
    const float* __restrict__ partial, int n, float* __restrict__ out)
{
    __shared__ double red[256];
    double s = 0.0;
    for (int i = threadIdx.x; i < n; i += 256) s += (double)partial[i];
    red[threadIdx.x] = s;
    __syncthreads();
    for (int off = 128; off > 0; off >>= 1) {
        if (threadIdx.x < off) red[threadIdx.x] += red[threadIdx.x + off];
        __syncthreads();
    }
    if (threadIdx.x == 0) out[0] = (float)(1.0 - red[0] / (double)NPLANE);
}

extern "C" void kernel_launch(void* const* d_in, const int* in_sizes, int n_in,
                              void* d_out, int out_size, void* d_ws, size_t ws_size,
                              hipStream_t stream) {
    const float* in  = (const float*)d_in[0];
    const float* tgt = (const float*)d_in[1];
    const float* wt  = (const float*)d_in[2];
    float* out  = (float*)d_out;
    float* part = (float*)d_ws;

    dim3 grid(NSTRIP, NPLANE);   // 32 strips x 48 planes = 1536 blocks
    ssim_strip<<<grid, 512, 0, stream>>>(in, tgt, wt, part);
    ssim_final<<<1, 256, 0, stream>>>(part, NSTRIP * NPLANE, out);
}

// Round 12
// 50.321 us; speedup vs baseline: 1.0164x; 1.0164x over previous
//
#include <hip/hip_runtime.h>

typedef float v2f __attribute__((ext_vector_type(2)));

#define IMG 512
#define OUT_N 502
#define NPLANE 48
#define NSTRIP 32            // 16 output rows per strip
#define SROWS 16
#define RPITCH 133           // region pitch (float4 units) in row buffer
#define ROWP (4*RPITCH)      // 532 float4 per buffered V-row
#define C1c 0.0001f
#define C2c 0.0004f

// ssim from H-blurred (Bs, Bd, BP, BM) where s=x+y, d=x-y:
// mux=(Bs+Bd)/2, muy=(Bs-Bd)/2; BP=blur(s^2), BM=blur(d^2).
// v_rcp_f32 for the final divide: den >= C1*C2 > 0; ~1e-6 rel err vs 1.125 tol.
__device__ __forceinline__ float ssim_px(float Bs, float Bd, float BP, float BM) {
    float mx = 0.5f*(Bs + Bd), my = 0.5f*(Bs - Bd);
    float A = mx*mx, B = my*my, mxy = mx*my;
    float sumsq = 0.5f*(BP + BM) - A - B;   // sigx2 + sigy2
    float sxy   = 0.25f*(BP - BM) - mxy;    // sigxy
    float num = (2.f*mxy + C1c) * (2.f*sxy + C2c);
    float den = (A + B + C1c) * (sumsq + C2c);
    return num * __builtin_amdgcn_rcpf(den);
}

// 512 threads, 1 col/thread in V, 4 cols/thread in H. 4-row barrier groups:
// V-blur 4 rows from a 16-entry (s,d) float2 ring (32 VGPR, &15 static slots),
// write one 4-row LDS buffer (mod-4 column regions, pitch 133: H reads are
// idx-stride-1 conflict-free, V writes uniform over bank-quads), barrier,
// H-pass 4 rows x 128 thr x 4 cols (14 b128 per 4 px = 3.5/px, was 6/px),
// barrier. Raw s_barrier + lgkmcnt only -- prefetched global loads (depth ~1
// group ahead) never drained at barriers.
__global__ __launch_bounds__(512, 3) void ssim_strip(
    const float* __restrict__ in, const float* __restrict__ tgt,
    const float* __restrict__ w, float* __restrict__ partial)
{
    __shared__ float4 buf[4*ROWP];      // 2128 float4 = 34 KB
    __shared__ float g1s[16];
    __shared__ float red[8];

    const int tid   = threadIdx.x;
    const int strip = blockIdx.x;
    const int plane = blockIdx.y;
    const int r0 = strip * SROWS;
    const float* __restrict__ ip = in  + (size_t)plane * (IMG*IMG);
    const float* __restrict__ tp = tgt + (size_t)plane * (IMG*IMG);

    // 1D factor = row sums of 2D kernel (exact: w2d = outer(g,g), sum g = 1)
    if (tid < 11) {
        float s = 0.f;
        #pragma unroll
        for (int j = 0; j < 11; ++j) s += w[tid*11 + j];
        g1s[tid] = s;
    }
    __syncthreads();
    float g[11];
    #pragma unroll
    for (int j = 0; j < 11; ++j)
        g[j] = __int_as_float(__builtin_amdgcn_readfirstlane(__float_as_int(g1s[j])));

    v2f sd[16];                 // ring: input row k -> slot k & 15 (static)
    float acc = 0.f;
    const int wbase = (tid & 3) * RPITCH + (tid >> 2);   // V-write addr (f4)
    const int hr = tid >> 7;    // H: row in group (0..3), wave-uniform
    const int ht = tid & 127;   // H: col group -> cols 4ht..4ht+3
    const int hb = hr * ROWP + ht;

#define LD1(ROW, X, Y) \
    { const int r_ = r0 + (ROW); \
      X = (r_ < IMG) ? ip[r_*IMG + tid] : 0.f; \
      Y = (r_ < IMG) ? tp[r_*IMG + tid] : 0.f; }

#define INS(ROW, X, Y) sd[(ROW) & 15] = (v2f){(X) + (Y), (X) - (Y)};

    // V-blur rows 4T..4T+3 (taps j: input row 4T+j feeds out-row v for
    // v<=j<=v+10, weight g[j-v]); squares shared by all 4 rows.
#define VWR(T) \
    { v2f a0=(v2f)(0.f),p0=(v2f)(0.f),a1=(v2f)(0.f),p1=(v2f)(0.f); \
      v2f a2=(v2f)(0.f),p2=(v2f)(0.f),a3=(v2f)(0.f),p3=(v2f)(0.f); \
      _Pragma("unroll") \
      for (int j = 0; j < 14; ++j) { \
        v2f s = sd[(4*(T) + j) & 15]; \
        v2f q = s * s; \
        if (j <= 10)           { const float wj=g[j];   a0+=wj*s; p0+=wj*q; } \
        if (j >= 1 && j <= 11) { const float wj=g[j-1]; a1+=wj*s; p1+=wj*q; } \
        if (j >= 2 && j <= 12) { const float wj=g[j-2]; a2+=wj*s; p2+=wj*q; } \
        if (j >= 3)            { const float wj=g[j-3]; a3+=wj*s; p3+=wj*q; } \
      } \
      buf[0*ROWP + wbase] = make_float4(a0.x, a0.y, p0.x, p0.y); \
      buf[1*ROWP + wbase] = make_float4(a1.x, a1.y, p1.x, p1.y); \
      buf[2*ROWP + wbase] = make_float4(a2.x, a2.y, p2.x, p2.y); \
      buf[3*ROWP + wbase] = make_float4(a3.x, a3.y, p3.x, p3.y); }

    // H-pass: tap col 4ht+j lives at region j&3, idx ht+(j>>2).
#define HPASS(T) \
    { v2f s0=(v2f)(0.f),q0=(v2f)(0.f),s1=(v2f)(0.f),q1=(v2f)(0.f); \
      v2f s2=(v2f)(0.f),q2=(v2f)(0.f),s3=(v2f)(0.f),q3=(v2f)(0.f); \
      _Pragma("unroll") \
      for (int j = 0; j < 14; ++j) { \
        float4 v = buf[hb + (j&3)*RPITCH + (j>>2)]; \
        v2f vs = (v2f){v.x, v.y}, vp = (v2f){v.z, v.w}; \
        if (j <= 10)           { const float wj=g[j];   s0+=wj*vs; q0+=wj*vp; } \
        if (j >= 1 && j <= 11) { const float wj=g[j-1]; s1+=wj*vs; q1+=wj*vp; } \
        if (j >= 2 && j <= 12) { const float wj=g[j-2]; s2+=wj*vs; q2+=wj*vp; } \
        if (j >= 3)            { const float wj=g[j-3]; s3+=wj*vs; q3+=wj*vp; } \
      } \
      const int oy = r0 + 4*(T) + hr; \
      const int oc = 4*ht; \
      if (oy < OUT_N) { \
        if (oc     < OUT_N) acc += ssim_px(s0.x,s0.y,q0.x,q0.y); \
        if (oc + 1 < OUT_N) acc += ssim_px(s1.x,s1.y,q1.x,q1.y); \
        if (oc + 2 < OUT_N) acc += ssim_px(s2.x,s2.y,q2.x,q2.y); \
        if (oc + 3 < OUT_N) acc += ssim_px(s3.x,s3.y,q3.x,q3.y); \
      } }

#define BARRIER() \
    asm volatile("s_waitcnt lgkmcnt(0)" ::: "memory"); \
    __builtin_amdgcn_s_barrier(); \
    __builtin_amdgcn_sched_barrier(0);

#define GISSUE(T) \
    LD1(4*(T)+14, f0x, f0y) LD1(4*(T)+15, f1x, f1y) \
    LD1(4*(T)+16, f2x, f2y) LD1(4*(T)+17, f3x, f3y)
#define GINSERT(T) \
    INS(4*(T)+14, f0x, f0y) INS(4*(T)+15, f1x, f1y) \
    INS(4*(T)+16, f2x, f2y) INS(4*(T)+17, f3x, f3y)

    float f0x, f0y, f1x, f1y, f2x, f2y, f3x, f3y;

    // Prologue: rows 0..13 into ring, depth-2 staggered issue.
    float ax, ay, bx, by;
    LD1(0, ax, ay)   LD1(1, bx, by)
    INS(0, ax, ay)   LD1(2, ax, ay)
    INS(1, bx, by)   LD1(3, bx, by)
    INS(2, ax, ay)   LD1(4, ax, ay)
    INS(3, bx, by)   LD1(5, bx, by)
    INS(4, ax, ay)   LD1(6, ax, ay)
    INS(5, bx, by)   LD1(7, bx, by)
    INS(6, ax, ay)   LD1(8, ax, ay)
    INS(7, bx, by)   LD1(9, bx, by)
    INS(8, ax, ay)   LD1(10, ax, ay)
    INS(9, bx, by)   LD1(11, bx, by)
    INS(10, ax, ay)  LD1(12, ax, ay)
    INS(11, bx, by)  LD1(13, bx, by)
    INS(12, ax, ay)  INS(13, bx, by)

    // 4 groups x 4 rows = 16 output rows. Loads for group T+1's new rows are
    // issued before VWR(T) and consumed after HPASS(T) (~1 group of slack).
    GISSUE(0) VWR(0) BARRIER() HPASS(0) GINSERT(0) BARRIER()
    GISSUE(1) VWR(1) BARRIER() HPASS(1) GINSERT(1) BARRIER()
    GISSUE(2) VWR(2) BARRIER() HPASS(2) GINSERT(2) BARRIER()
              VWR(3) BARRIER() HPASS(3)

    // block reduction: wave shuffle, then 8 wave-partials through LDS
    #pragma unroll
    for (int off = 32; off > 0; off >>= 1)
        acc += __shfl_down(acc, off, 64);
    const int lane = tid & 63, wv = tid >> 6;
    if (lane == 0) red[wv] = acc;
    __syncthreads();
    if (tid == 0) {
        float t = 0.f;
        #pragma unroll
        for (int i = 0; i < 8; ++i) t += red[i];
        partial[plane * NSTRIP + strip] = t;
    }
}

// Deterministic final reduction: fixed traversal, double accumulation.
__global__ __launch_bounds__(256) void ssim_final(
    const float* __restrict__ partial, int n, float* __restrict__ out)
{
    __shared__ double red[256];
    double s = 0.0;
    for (int i = threadIdx.x; i < n; i += 256) s += (double)partial[i];
    red[threadIdx.x] = s;
    __syncthreads();
    for (int off = 128; off > 0; off >>= 1) {
        if (threadIdx.x < off) red[threadIdx.x] += red[threadIdx.x + off];
        __syncthreads();
    }
    if (threadIdx.x == 0) out[0] = (float)(1.0 - red[0] / (double)NPLANE);
}

extern "C" void kernel_launch(void* const* d_in, const int* in_sizes, int n_in,
                              void* d_out, int out_size, void* d_ws, size_t ws_size,
                              hipStream_t stream) {
    const float* in  = (const float*)d_in[0];
    const float* tgt = (const float*)d_in[1];
    const float* wt  = (const float*)d_in[2];
    float* out  = (float*)d_out;
    float* part = (float*)d_ws;

    dim3 grid(NSTRIP, NPLANE);   // 32 strips x 48 planes = 1536 blocks
    ssim_strip<<<grid, 512, 0, stream>>>(in, tgt, wt, part);
    ssim_final<<<1, 256, 0, stream>>>(part, NSTRIP * NPLANE, out);
}